// Round 4
// baseline (1095.064 us; speedup 1.0000x reference)
//
#include <hip/hip_runtime.h>
#include <hip/hip_bf16.h>

typedef __attribute__((ext_vector_type(8))) short bf16x8;
typedef __attribute__((ext_vector_type(4))) float f32x4;

#define DEVI __device__ __forceinline__

DEVI unsigned short f2bf_bits(float f) {
    __hip_bfloat16 h = __float2bfloat16(f);
    return *reinterpret_cast<unsigned short*>(&h);
}

// async global->LDS, 16B per lane. LDS dest is wave-uniform base + lane*16.
DEVI void gload_lds16(const void* g, void* lds) {
    __builtin_amdgcn_global_load_lds(
        (const __attribute__((address_space(1))) unsigned int*)g,
        (__attribute__((address_space(3))) unsigned int*)lds, 16, 0, 0);
}

// ---------------- patchify: x[B,C,384,384] -> patches bf16 [4608][1536] ----------------
__global__ __launch_bounds__(256) void patchify_kernel(const float* __restrict__ x,
                                                       unsigned short* __restrict__ patches)
{
    size_t i = (size_t)blockIdx.x * 256 + threadIdx.x;   // 8*6*384*384 = 7,077,888 exactly
    int j = (int)(i % 384);
    size_t t = i / 384;
    int r = (int)(t % 384); t /= 384;
    int c = (int)(t % 6);
    int b = (int)(t / 6);
    int gh = r >> 4, p1 = r & 15, gw = j >> 4, p2 = j & 15;
    int prow = b * 576 + gh * 24 + gw;
    int pcol = (p1 * 16 + p2) * 6 + c;
    patches[(size_t)prow * 1536 + pcol] = f2bf_bits(x[i]);
}

// ---------------- weight convert + transpose: W f32 [K][N] -> Wt bf16 [N][K] ----------------
DEVI void convT_body(const float* __restrict__ W, __hip_bfloat16* __restrict__ Wt,
                     int K, int N, int k0, int n0, int tid)
{
    __shared__ float tile[32][33];
    int tx = tid & 31, ty = tid >> 5;   // ty 0..7
#pragma unroll
    for (int i = 0; i < 4; i++)
        tile[ty + 8 * i][tx] = W[(size_t)(k0 + ty + 8 * i) * N + n0 + tx];
    __syncthreads();
#pragma unroll
    for (int i = 0; i < 4; i++)
        Wt[(size_t)(n0 + ty + 8 * i) * K + k0 + tx] = __float2bfloat16(tile[tx][ty + 8 * i]);
}

__global__ __launch_bounds__(256) void convT_kernel(const float* __restrict__ W,
                                                    __hip_bfloat16* __restrict__ Wt,
                                                    int K, int N)
{
    convT_body(W, Wt, K, N, blockIdx.y * 32, blockIdx.x * 32, threadIdx.x);
}

// one dispatch converts all 4 weights of a layer into lw (layer-weight buffer):
//   [0)        qkv^T  [2304][768]
//   [1769472)  wout^T [768][768]
//   [2359296)  w1^T   [3072][768]
//   [4718592)  w2^T   [768][3072]
__global__ __launch_bounds__(256) void convT4_kernel(const float* __restrict__ wqkv,
                                                     const float* __restrict__ wout,
                                                     const float* __restrict__ w1,
                                                     const float* __restrict__ w2,
                                                     __hip_bfloat16* __restrict__ dst)
{
    int bt = blockIdx.x;
    const float* W; __hip_bfloat16* Wt; int K, N, lt;
    if (bt < 1728)      { W = wqkv; K = 768;  N = 2304; lt = bt;        Wt = dst; }
    else if (bt < 2304) { W = wout; K = 768;  N = 768;  lt = bt - 1728; Wt = dst + 1769472; }
    else if (bt < 4608) { W = w1;   K = 768;  N = 3072; lt = bt - 2304; Wt = dst + 2359296; }
    else                { W = w2;   K = 3072; N = 768;  lt = bt - 4608; Wt = dst + 4718592; }
    int tn = N >> 5;
    convT_body(W, Wt, K, N, (lt / tn) * 32, (lt % tn) * 32, threadIdx.x);
}

// ---------------- layernorm over 768 cols ----------------
DEVI void st_ln(float* p, float v) { *p = v; }
DEVI void st_ln(__hip_bfloat16* p, float v) { *p = __float2bfloat16(v); }

template <typename OutT>
__global__ __launch_bounds__(256) void ln_kernel(const float* __restrict__ x,
                                                 const float* __restrict__ g,
                                                 const float* __restrict__ b,
                                                 OutT* __restrict__ out)
{
    int row = blockIdx.x, tid = threadIdx.x;
    const float* xr = x + (size_t)row * 768;
    float v0 = xr[tid], v1 = xr[tid + 256], v2 = xr[tid + 512];
    float s = v0 + v1 + v2;
    float s2 = v0 * v0 + v1 * v1 + v2 * v2;
#pragma unroll
    for (int m = 32; m >= 1; m >>= 1) { s += __shfl_xor(s, m); s2 += __shfl_xor(s2, m); }
    __shared__ float red[8];
    int w = tid >> 6;
    if ((tid & 63) == 0) { red[w] = s; red[4 + w] = s2; }
    __syncthreads();
    s = red[0] + red[1] + red[2] + red[3];
    s2 = red[4] + red[5] + red[6] + red[7];
    float mean = s * (1.0f / 768.0f);
    float var = s2 * (1.0f / 768.0f) - mean * mean;
    float rstd = rsqrtf(var + 1e-5f);
    OutT* orow = out + (size_t)row * 768;
    st_ln(&orow[tid], (v0 - mean) * rstd * g[tid] + b[tid]);
    st_ln(&orow[tid + 256], (v1 - mean) * rstd * g[tid + 256] + b[tid + 256]);
    st_ln(&orow[tid + 512], (v2 - mean) * rstd * g[tid + 512] + b[tid + 512]);
}

// ---------------- bf16 MFMA GEMM, counted-vmcnt double-buffered pipeline (T3+T4) ----------------
// C[M,N] = A[M,K] @ Bt[N,K]^T. Tile BM x 128, BK=32, 4 waves (2x2), linear LDS,
// global_load_lds width 16. Steady state keeps 2 tiles in flight; vmcnt never drains
// to 0 in the main loop (waits only the next tile's SL loads), so HBM latency spans
// the raw s_barriers instead of serializing at them.
template <int BM, bool BIAS, bool RESID, bool GELU, bool BF16OUT>
__global__ __launch_bounds__(256) void gemm_bt_kernel(
    const __hip_bfloat16* __restrict__ A,
    const __hip_bfloat16* __restrict__ Bt,
    const float* __restrict__ bias,
    const float* __restrict__ resid,
    float* __restrict__ Cf,
    __hip_bfloat16* __restrict__ Cb,
    int M, int N, int K)
{
    constexpr int MREP = BM / 32;
    constexpr int SL = BM / 64 + 2;   // stage loads per thread per tile
    __shared__ __align__(16) __hip_bfloat16 As[2][BM * 32];
    __shared__ __align__(16) __hip_bfloat16 Bs[2][128 * 32];
    const int tid = threadIdx.x;
    const int wid = tid >> 6, lane = tid & 63;
    const int g = lane >> 4, l16 = lane & 15;
    const int wm = (wid >> 1) * (BM / 2), wn = (wid & 1) * 64;
    const int bm = blockIdx.y * BM, bn = blockIdx.x * 128;
    const int sr = tid >> 2, sc = (tid & 3) * 8;   // 256 thr = 64 rows x 64B per round

    f32x4 acc[MREP][4] = {};
    const int nt = K >> 5;             // all K here are multiples of 32, nt >= 2

    auto stage = [&](int buf, int t) {
        const int k0 = t * 32;
#pragma unroll
        for (int i = 0; i < BM / 64; i++)
            gload_lds16(&A[(size_t)(bm + i * 64 + sr) * K + k0 + sc], &As[buf][(i * 64 + sr) * 32 + sc]);
#pragma unroll
        for (int i = 0; i < 2; i++)
            gload_lds16(&Bt[(size_t)(bn + i * 64 + sr) * K + k0 + sc], &Bs[buf][(i * 64 + sr) * 32 + sc]);
    };

#define WAIT_VM_SL()                                                        \
    do {                                                                    \
        if constexpr (SL == 4) asm volatile("s_waitcnt vmcnt(4)" ::: "memory"); \
        else                   asm volatile("s_waitcnt vmcnt(3)" ::: "memory"); \
        __builtin_amdgcn_sched_barrier(0);                                  \
    } while (0)

    stage(0, 0);
    stage(1, 1);
    WAIT_VM_SL();                       // tile 0 landed; tile 1 still in flight
    __builtin_amdgcn_s_barrier();
    __builtin_amdgcn_sched_barrier(0);

    for (int t = 0; t < nt; t++) {
        const int cur = t & 1;
        bf16x8 af[MREP], bfr[4];
#pragma unroll
        for (int mi = 0; mi < MREP; mi++)
            af[mi] = *(const bf16x8*)&As[cur][(wm + mi * 16 + l16) * 32 + g * 8];
#pragma unroll
        for (int ni = 0; ni < 4; ni++)
            bfr[ni] = *(const bf16x8*)&Bs[cur][(wn + ni * 16 + l16) * 32 + g * 8];
#pragma unroll
        for (int mi = 0; mi < MREP; mi++)
#pragma unroll
            for (int ni = 0; ni < 4; ni++)
                acc[mi][ni] = __builtin_amdgcn_mfma_f32_16x16x32_bf16(af[mi], bfr[ni], acc[mi][ni], 0, 0, 0);

        // all my LDS reads of buf[cur] drained before signaling others may overwrite it
        asm volatile("s_waitcnt lgkmcnt(0)" ::: "memory");
        __builtin_amdgcn_sched_barrier(0);
        __builtin_amdgcn_s_barrier();
        __builtin_amdgcn_sched_barrier(0);

        if (t + 2 < nt) stage(cur, t + 2);
        if (t + 1 < nt) {
            if (t + 2 < nt) {
                WAIT_VM_SL();           // tile t+1 landed; t+2 stays in flight
            } else {
                asm volatile("s_waitcnt vmcnt(0)" ::: "memory");
                __builtin_amdgcn_sched_barrier(0);
            }
            __builtin_amdgcn_s_barrier();
            __builtin_amdgcn_sched_barrier(0);
        }
    }
#undef WAIT_VM_SL

#pragma unroll
    for (int mi = 0; mi < MREP; mi++) {
#pragma unroll
        for (int ni = 0; ni < 4; ni++) {
            int gcol = bn + wn + ni * 16 + l16;
            float bval = 0.0f;
            if (BIAS) bval = bias[gcol];
#pragma unroll
            for (int r = 0; r < 4; r++) {
                int grow = bm + wm + mi * 16 + 4 * g + r;   // C/D: row=(lane>>4)*4+reg, col=lane&15
                float v = acc[mi][ni][r] + bval;
                if (GELU) v = 0.5f * v * (1.0f + erff(v * 0.70710678118654752f));
                if (RESID) v += resid[(size_t)grow * N + gcol];
                if (BF16OUT) Cb[(size_t)grow * N + gcol] = __float2bfloat16(v);
                else Cf[(size_t)grow * N + gcol] = v;
            }
        }
    }
}

// ---------------- MFMA flash attention: softmax(q@k^T*scale + bias) @ v ----------------
DEVI void stage16f(const float* __restrict__ src, __hip_bfloat16* dst)
{
#pragma unroll
    for (int i = 0; i < 4; i++) {
        float4 v = ((const float4*)src)[i];
        ushort4 u = { f2bf_bits(v.x), f2bf_bits(v.y), f2bf_bits(v.z), f2bf_bits(v.w) };
        ((ushort4*)dst)[i] = u;
    }
}

__global__ __launch_bounds__(256) void attn_kernel(const float* __restrict__ qkv,
                                                   const float* __restrict__ bias,   // [12][576][576] this layer
                                                   unsigned short* __restrict__ o)   // bf16 [4608][768]
{
    const int qt = blockIdx.x, h = blockIdx.y, bb = blockIdx.z;
    const int q0 = qt * 64;
    const int tid = threadIdx.x;
    const int wq = tid >> 6, lane = tid & 63, g = lane >> 4, l16 = lane & 15;

    __shared__ __align__(16) __hip_bfloat16 Qs[64 * 72];
    __shared__ __align__(16) __hip_bfloat16 Ks[64 * 72];
    __shared__ __align__(16) __hip_bfloat16 Vt[64 * 72];    // V^T: [d][key]
    __shared__ __align__(16) __hip_bfloat16 Ps[4][16 * 72]; // per-wave P tile [qrow][key]

    {
        int r = tid >> 2, cb = (tid & 3) * 16;
        stage16f(&qkv[(size_t)(bb * 576 + q0 + r) * 2304 + h * 64 + cb], &Qs[r * 72 + cb]);
    }
    __syncthreads();
    bf16x8 qf0 = *(const bf16x8*)&Qs[(wq * 16 + l16) * 72 + g * 8];
    bf16x8 qf1 = *(const bf16x8*)&Qs[(wq * 16 + l16) * 72 + 32 + g * 8];

    float m_r[4] = {-1e30f, -1e30f, -1e30f, -1e30f};
    float l_r[4] = {0.f, 0.f, 0.f, 0.f};
    f32x4 oa[4] = {};
    const float* bias_h = bias + (size_t)h * 576 * 576;
    const float scale = 0.125f;

    for (int kt = 0; kt < 576; kt += 64) {
        {
            int r = tid >> 2, cb = (tid & 3) * 16;
            stage16f(&qkv[(size_t)(bb * 576 + kt + r) * 2304 + 768 + h * 64 + cb], &Ks[r * 72 + cb]);
            int key = tid & 63, d0 = (tid >> 6) * 16;
            const float* vs = &qkv[(size_t)(bb * 576 + kt + key) * 2304 + 1536 + h * 64 + d0];
#pragma unroll
            for (int i = 0; i < 4; i++) {
                float4 v = ((const float4*)vs)[i];
                Vt[(d0 + 4 * i + 0) * 72 + key] = __float2bfloat16(v.x);
                Vt[(d0 + 4 * i + 1) * 72 + key] = __float2bfloat16(v.y);
                Vt[(d0 + 4 * i + 2) * 72 + key] = __float2bfloat16(v.z);
                Vt[(d0 + 4 * i + 3) * 72 + key] = __float2bfloat16(v.w);
            }
        }
        __syncthreads();

        float bl[4][4];
#pragma unroll
        for (int kc = 0; kc < 4; kc++)
#pragma unroll
            for (int r = 0; r < 4; r++) {
                int q = q0 + wq * 16 + 4 * g + r;
                bl[kc][r] = bias_h[(size_t)q * 576 + kt + kc * 16 + l16];
            }

        f32x4 sc[4] = {};
#pragma unroll
        for (int kc = 0; kc < 4; kc++) {
            bf16x8 kf0 = *(const bf16x8*)&Ks[(kc * 16 + l16) * 72 + g * 8];
            bf16x8 kf1 = *(const bf16x8*)&Ks[(kc * 16 + l16) * 72 + 32 + g * 8];
            sc[kc] = __builtin_amdgcn_mfma_f32_16x16x32_bf16(qf0, kf0, sc[kc], 0, 0, 0);
            sc[kc] = __builtin_amdgcn_mfma_f32_16x16x32_bf16(qf1, kf1, sc[kc], 0, 0, 0);
        }

        float sv[4][4], mt[4] = {-1e30f, -1e30f, -1e30f, -1e30f};
#pragma unroll
        for (int kc = 0; kc < 4; kc++)
#pragma unroll
            for (int r = 0; r < 4; r++) {
                float s = sc[kc][r] * scale + bl[kc][r];
                sv[kc][r] = s;
                mt[r] = fmaxf(mt[r], s);
            }
#pragma unroll
        for (int r = 0; r < 4; r++)
#pragma unroll
            for (int m = 1; m < 16; m <<= 1) mt[r] = fmaxf(mt[r], __shfl_xor(mt[r], m));

        float sf[4];
#pragma unroll
        for (int r = 0; r < 4; r++) {
            float mn = fmaxf(m_r[r], mt[r]);
            sf[r] = __expf(m_r[r] - mn);
            m_r[r] = mn;
        }
        float rs[4] = {0.f, 0.f, 0.f, 0.f};
#pragma unroll
        for (int kc = 0; kc < 4; kc++)
#pragma unroll
            for (int r = 0; r < 4; r++) {
                float p = __expf(sv[kc][r] - m_r[r]);
                rs[r] += p;
                Ps[wq][(4 * g + r) * 72 + kc * 16 + l16] = __float2bfloat16(p);
            }
#pragma unroll
        for (int r = 0; r < 4; r++) {
#pragma unroll
            for (int m = 1; m < 16; m <<= 1) rs[r] += __shfl_xor(rs[r], m);
            l_r[r] = l_r[r] * sf[r] + rs[r];
        }
#pragma unroll
        for (int dt = 0; dt < 4; dt++)
#pragma unroll
            for (int r = 0; r < 4; r++) oa[dt][r] *= sf[r];

        asm volatile("s_waitcnt lgkmcnt(0)" ::: "memory");

#pragma unroll
        for (int s = 0; s < 2; s++) {
            bf16x8 pf = *(const bf16x8*)&Ps[wq][l16 * 72 + s * 32 + g * 8];
#pragma unroll
            for (int dt = 0; dt < 4; dt++) {
                bf16x8 vf = *(const bf16x8*)&Vt[(dt * 16 + l16) * 72 + s * 32 + g * 8];
                oa[dt] = __builtin_amdgcn_mfma_f32_16x16x32_bf16(pf, vf, oa[dt], 0, 0, 0);
            }
        }
        __syncthreads();
    }

#pragma unroll
    for (int dt = 0; dt < 4; dt++)
#pragma unroll
        for (int r = 0; r < 4; r++) {
            int q = q0 + wq * 16 + 4 * g + r;
            float v = oa[dt][r] / l_r[r];
            o[(size_t)(bb * 576 + q) * 768 + h * 64 + dt * 16 + l16] = f2bf_bits(v);
        }
}

// ---------------- mean pool over 576 tokens ----------------
__global__ __launch_bounds__(256) void pool_kernel(const float* __restrict__ tok, float* __restrict__ pooled)
{
    int d = blockIdx.x * 256 + threadIdx.x;   // grid.x = 3
    int b = blockIdx.y;
    float s = 0.0f;
    for (int n = 0; n < 576; n++) s += tok[(size_t)(b * 576 + n) * 768 + d];
    pooled[b * 768 + d] = s * (1.0f / 576.0f);
}

// ---------------- classifier head ----------------
__global__ __launch_bounds__(256) void head_kernel(const float* __restrict__ lnp,
                                                   const float* __restrict__ w,
                                                   const float* __restrict__ bh,
                                                   float* __restrict__ out)
{
    int c = blockIdx.x * 256 + threadIdx.x;
    int b = blockIdx.y;
    if (c >= 1000) return;
    float s = bh[c];
    for (int d = 0; d < 768; d++) s += lnp[b * 768 + d] * w[(size_t)d * 1000 + c];
    out[b * 1000 + c] = s;
}

extern "C" void kernel_launch(void* const* d_in, const int* in_sizes, int n_in,
                              void* d_out, int out_size, void* d_ws, size_t ws_size,
                              hipStream_t stream)
{
    const float* x = (const float*)d_in[0];
    const float* patch_w = (const float*)d_in[1];
    const float* patch_b = (const float*)d_in[2];
    const float* ln1_g = (const float*)d_in[3];
    const float* ln1_b = (const float*)d_in[4];
    const float* w_qkv = (const float*)d_in[5];
    const float* bias_att = (const float*)d_in[6];
    const float* w_out = (const float*)d_in[7];
    const float* ln2_g = (const float*)d_in[8];
    const float* ln2_b = (const float*)d_in[9];
    const float* w1 = (const float*)d_in[10];
    const float* b1 = (const float*)d_in[11];
    const float* w2 = (const float*)d_in[12];
    const float* b2 = (const float*)d_in[13];
    const float* lnh_g = (const float*)d_in[14];
    const float* lnh_b = (const float*)d_in[15];
    const float* w_head = (const float*)d_in[16];
    const float* b_head = (const float*)d_in[17];
    float* out = (float*)d_out;

    char* ws = (char*)d_ws;
    float* tok = (float*)(ws + 0);                               // 4608*768 f32   = 14,155,776 B
    float* qkv = (float*)(ws + 14155776);                        // 4608*2304 f32  = 42,467,328 B
    float* pooled = (float*)(ws + 56623104);                     // 8*768 f32
    float* pooledln = (float*)(ws + 56647680);                   // 8*768 f32
    __hip_bfloat16* patches = (__hip_bfloat16*)(ws + 56672256);  // 4608*1536 bf16 = 14,155,776 B
    __hip_bfloat16* lw = patches;                                // layer weights reuse patches region
                                                                 // after patch-embed GEMM (stream-serial):
                                                                 // 7,077,888 bf16 = 14,155,776 B exactly
    __hip_bfloat16* h_bf = (__hip_bfloat16*)(ws + 70828032);     // 4608*768 bf16  =  7,077,888 B
    __hip_bfloat16* o_bf = (__hip_bfloat16*)(ws + 77905920);     // 4608*768 bf16  =  7,077,888 B
    __hip_bfloat16* hid_bf = (__hip_bfloat16*)(ws + 84983808);   // 4608*3072 bf16 = 28,311,552 B
    __hip_bfloat16* wbuf = (__hip_bfloat16*)(ws + 113295360);    // patch weight: 1536*768 bf16

    // patch embedding
    patchify_kernel<<<27648, 256, 0, stream>>>(x, (unsigned short*)patches);
    convT_kernel<<<dim3(768 / 32, 1536 / 32), 256, 0, stream>>>(patch_w, wbuf, 1536, 768);
    gemm_bt_kernel<64, true, false, false, false><<<dim3(6, 72), 256, 0, stream>>>(
        patches, wbuf, patch_b, nullptr, tok, nullptr, 4608, 768, 1536);

    for (int l = 0; l < 4; l++) {
        // all 4 weight converts of this layer in one dispatch (into lw, patches now dead)
        convT4_kernel<<<6912, 256, 0, stream>>>(
            w_qkv + (size_t)l * 768 * 2304, w_out + (size_t)l * 768 * 768,
            w1 + (size_t)l * 768 * 3072, w2 + (size_t)l * 3072 * 768, lw);
        // attn sub-block
        ln_kernel<__hip_bfloat16><<<4608, 256, 0, stream>>>(tok, ln1_g + l * 768, ln1_b + l * 768, h_bf);
        gemm_bt_kernel<128, false, false, false, false><<<dim3(18, 36), 256, 0, stream>>>(
            h_bf, lw, nullptr, nullptr, qkv, nullptr, 4608, 2304, 768);
        attn_kernel<<<dim3(9, 12, 8), 256, 0, stream>>>(
            qkv, bias_att + (size_t)l * 12 * 576 * 576, (unsigned short*)o_bf);
        gemm_bt_kernel<64, false, true, false, false><<<dim3(6, 72), 256, 0, stream>>>(
            o_bf, lw + 1769472, nullptr, tok, tok, nullptr, 4608, 768, 768);
        // mlp sub-block
        ln_kernel<__hip_bfloat16><<<4608, 256, 0, stream>>>(tok, ln2_g + l * 768, ln2_b + l * 768, h_bf);
        gemm_bt_kernel<128, true, false, true, true><<<dim3(24, 36), 256, 0, stream>>>(
            h_bf, lw + 2359296, b1 + l * 3072, nullptr, nullptr, hid_bf, 4608, 3072, 768);
        gemm_bt_kernel<64, true, true, false, false><<<dim3(6, 72), 256, 0, stream>>>(
            hid_bf, lw + 4718592, b2 + l * 768, tok, tok, nullptr, 4608, 768, 3072);
    }

    pool_kernel<<<dim3(3, 8), 256, 0, stream>>>(tok, pooled);
    ln_kernel<float><<<8, 256, 0, stream>>>(pooled, lnh_g, lnh_b, pooledln);
    head_kernel<<<dim3(4, 8), 256, 0, stream>>>(pooledln, w_head, b_head, out);
}

// Round 5
// 921.197 us; speedup vs baseline: 1.1887x; 1.1887x over previous
//
#include <hip/hip_runtime.h>
#include <hip/hip_bf16.h>

typedef __attribute__((ext_vector_type(8))) short bf16x8;
typedef __attribute__((ext_vector_type(4))) float f32x4;

#define DEVI __device__ __forceinline__

DEVI unsigned short f2bf_bits(float f) {
    __hip_bfloat16 h = __float2bfloat16(f);
    return *reinterpret_cast<unsigned short*>(&h);
}

// async global->LDS, 16B per lane. LDS dest is wave-uniform base + lane*16 (linear).
DEVI void gload_lds16(const void* g, void* lds) {
    __builtin_amdgcn_global_load_lds(
        (const __attribute__((address_space(1))) unsigned int*)g,
        (__attribute__((address_space(3))) unsigned int*)lds, 16, 0, 0);
}

template <int N> DEVI void wait_vm() {
    if constexpr (N == 0) asm volatile("s_waitcnt vmcnt(0)" ::: "memory");
    else if constexpr (N == 3) asm volatile("s_waitcnt vmcnt(3)" ::: "memory");
    else if constexpr (N == 4) asm volatile("s_waitcnt vmcnt(4)" ::: "memory");
    else if constexpr (N == 6) asm volatile("s_waitcnt vmcnt(6)" ::: "memory");
    else if constexpr (N == 8) asm volatile("s_waitcnt vmcnt(8)" ::: "memory");
    __builtin_amdgcn_sched_barrier(0);
}

// ---------------- patchify: x[B,C,384,384] -> patches bf16 [4608][1536] ----------------
__global__ __launch_bounds__(256) void patchify_kernel(const float* __restrict__ x,
                                                       unsigned short* __restrict__ patches)
{
    size_t i = (size_t)blockIdx.x * 256 + threadIdx.x;   // 8*6*384*384 = 7,077,888 exactly
    int j = (int)(i % 384);
    size_t t = i / 384;
    int r = (int)(t % 384); t /= 384;
    int c = (int)(t % 6);
    int b = (int)(t / 6);
    int gh = r >> 4, p1 = r & 15, gw = j >> 4, p2 = j & 15;
    int prow = b * 576 + gh * 24 + gw;
    int pcol = (p1 * 16 + p2) * 6 + c;
    patches[(size_t)prow * 1536 + pcol] = f2bf_bits(x[i]);
}

// ---------------- weight convert + transpose: W f32 [K][N] -> Wt bf16 [N][K] ----------------
DEVI void convT_body(const float* __restrict__ W, __hip_bfloat16* __restrict__ Wt,
                     int K, int N, int k0, int n0, int tid)
{
    __shared__ float tile[32][33];
    int tx = tid & 31, ty = tid >> 5;   // ty 0..7
#pragma unroll
    for (int i = 0; i < 4; i++)
        tile[ty + 8 * i][tx] = W[(size_t)(k0 + ty + 8 * i) * N + n0 + tx];
    __syncthreads();
#pragma unroll
    for (int i = 0; i < 4; i++)
        Wt[(size_t)(n0 + ty + 8 * i) * K + k0 + tx] = __float2bfloat16(tile[tx][ty + 8 * i]);
}

__global__ __launch_bounds__(256) void convT_kernel(const float* __restrict__ W,
                                                    __hip_bfloat16* __restrict__ Wt,
                                                    int K, int N)
{
    convT_body(W, Wt, K, N, blockIdx.y * 32, blockIdx.x * 32, threadIdx.x);
}

// one dispatch converts all 4 weights of a layer into lw:
//   [0) qkv^T [2304][768]  [1769472) wout^T [768][768]
//   [2359296) w1^T [3072][768]  [4718592) w2^T [768][3072]
__global__ __launch_bounds__(256) void convT4_kernel(const float* __restrict__ wqkv,
                                                     const float* __restrict__ wout,
                                                     const float* __restrict__ w1,
                                                     const float* __restrict__ w2,
                                                     __hip_bfloat16* __restrict__ dst)
{
    int bt = blockIdx.x;
    const float* W; __hip_bfloat16* Wt; int K, N, lt;
    if (bt < 1728)      { W = wqkv; K = 768;  N = 2304; lt = bt;        Wt = dst; }
    else if (bt < 2304) { W = wout; K = 768;  N = 768;  lt = bt - 1728; Wt = dst + 1769472; }
    else if (bt < 4608) { W = w1;   K = 768;  N = 3072; lt = bt - 2304; Wt = dst + 2359296; }
    else                { W = w2;   K = 3072; N = 768;  lt = bt - 4608; Wt = dst + 4718592; }
    int tn = N >> 5;
    convT_body(W, Wt, K, N, (lt / tn) * 32, (lt % tn) * 32, threadIdx.x);
}

// ---------------- layernorm over 768 cols ----------------
DEVI void st_ln(float* p, float v) { *p = v; }
DEVI void st_ln(__hip_bfloat16* p, float v) { *p = __float2bfloat16(v); }

template <typename OutT>
__global__ __launch_bounds__(256) void ln_kernel(const float* __restrict__ x,
                                                 const float* __restrict__ g,
                                                 const float* __restrict__ b,
                                                 OutT* __restrict__ out)
{
    int row = blockIdx.x, tid = threadIdx.x;
    const float* xr = x + (size_t)row * 768;
    float v0 = xr[tid], v1 = xr[tid + 256], v2 = xr[tid + 512];
    float s = v0 + v1 + v2;
    float s2 = v0 * v0 + v1 * v1 + v2 * v2;
#pragma unroll
    for (int m = 32; m >= 1; m >>= 1) { s += __shfl_xor(s, m); s2 += __shfl_xor(s2, m); }
    __shared__ float red[8];
    int w = tid >> 6;
    if ((tid & 63) == 0) { red[w] = s; red[4 + w] = s2; }
    __syncthreads();
    s = red[0] + red[1] + red[2] + red[3];
    s2 = red[4] + red[5] + red[6] + red[7];
    float mean = s * (1.0f / 768.0f);
    float var = s2 * (1.0f / 768.0f) - mean * mean;
    float rstd = rsqrtf(var + 1e-5f);
    OutT* orow = out + (size_t)row * 768;
    st_ln(&orow[tid], (v0 - mean) * rstd * g[tid] + b[tid]);
    st_ln(&orow[tid + 256], (v1 - mean) * rstd * g[tid + 256] + b[tid + 256]);
    st_ln(&orow[tid + 512], (v2 - mean) * rstd * g[tid + 512] + b[tid + 512]);
}

// ---------------- bf16 MFMA GEMM, 3-deep counted-vmcnt pipeline + chunk-swizzled LDS ----------
// C[M,N] = A[M,K] @ Bt[N,K]^T. Tile BM x 128, BK=32, 4 waves (2x2). LDS rows are 64B (4 chunks
// of 16B); chunk of row r holding global chunk c sits at position c ^ ((r>>1)&3) — applied on
// the global SOURCE address (gload_lds dest stays linear, rule both-sides-or-neither) and on
// the ds_read position. Read conflict: 8-way -> 2-way (free). 3 buffers, steady-state
// vmcnt(2*SL): two tiles always in flight across barriers. nt must be divisible by 3.
template <int BM, bool BIAS, bool RESID, bool GELU, bool BF16OUT>
__global__ __launch_bounds__(256, 3) void gemm_bt_kernel(
    const __hip_bfloat16* __restrict__ A,
    const __hip_bfloat16* __restrict__ Bt,
    const float* __restrict__ bias,
    const float* __restrict__ resid,
    float* __restrict__ Cf,
    __hip_bfloat16* __restrict__ Cb,
    int M, int N, int K, int gx, int chunk)
{
    constexpr int MREP = BM / 32;
    constexpr int SL = BM / 64 + 2;   // gload calls per thread per tile
    __shared__ __align__(16) __hip_bfloat16 As[3][BM * 32];
    __shared__ __align__(16) __hip_bfloat16 Bs[3][128 * 32];
    const int tid = threadIdx.x;
    const int wid = tid >> 6, lane = tid & 63;
    const int g = lane >> 4, l16 = lane & 15;
    const int wm = (wid >> 1) * (BM / 2), wn = (wid & 1) * 64;

    // XCD-chunked bijective remap (grid divisible by 8)
    const int seq = (blockIdx.x & 7) * chunk + (blockIdx.x >> 3);
    const int bm = (seq / gx) * BM, bn = (seq % gx) * 128;

    // staging geometry: per call a wave writes 16 rows x 64B linear; source chunk swizzled
    const int sr = tid >> 2;                       // row within 64-row group
    const int csrc = (lane & 3) ^ ((lane >> 3) & 3);
    const int sdst = sr * 32 + (lane & 3) * 8;     // element offset in [64*32] group
    size_t aOff[BM / 64], bOff[2];
#pragma unroll
    for (int i = 0; i < BM / 64; i++) aOff[i] = (size_t)(bm + i * 64 + sr) * K + csrc * 8;
#pragma unroll
    for (int i = 0; i < 2; i++)       bOff[i] = (size_t)(bn + i * 64 + sr) * K + csrc * 8;

    auto stage = [&](__hip_bfloat16* asb, __hip_bfloat16* bsb, int tq) {
        const __hip_bfloat16* ap = A + tq * 32;
        const __hip_bfloat16* bp = Bt + tq * 32;
#pragma unroll
        for (int i = 0; i < BM / 64; i++) gload_lds16(ap + aOff[i], asb + i * 2048 + sdst);
#pragma unroll
        for (int i = 0; i < 2; i++)       gload_lds16(bp + bOff[i], bsb + i * 2048 + sdst);
    };

    // fragment read offsets (swizzled chunk position)
    const int pSw = (l16 >> 1) & 3;
    f32x4 acc[MREP][4] = {};
    const int nt = K >> 5;   // divisible by 3 for all K used (768/1536/3072)

    stage(As[0], Bs[0], 0);
    stage(As[1], Bs[1], 1);
    stage(As[2], Bs[2], 2);
    wait_vm<2 * SL>();
    __builtin_amdgcn_s_barrier();
    __builtin_amdgcn_sched_barrier(0);

    for (int t = 0; t < nt; t += 3) {
#pragma unroll
        for (int u = 0; u < 3; u++) {
            const int tc = t + u;
            bf16x8 af[MREP], bfr[4];
#pragma unroll
            for (int mi = 0; mi < MREP; mi++)
                af[mi] = *(const bf16x8*)&As[u][(wm + mi * 16 + l16) * 32 + ((g ^ pSw) << 3)];
#pragma unroll
            for (int ni = 0; ni < 4; ni++)
                bfr[ni] = *(const bf16x8*)&Bs[u][(wn + ni * 16 + l16) * 32 + ((g ^ pSw) << 3)];
#pragma unroll
            for (int mi = 0; mi < MREP; mi++)
#pragma unroll
                for (int ni = 0; ni < 4; ni++)
                    acc[mi][ni] = __builtin_amdgcn_mfma_f32_16x16x32_bf16(af[mi], bfr[ni], acc[mi][ni], 0, 0, 0);

            // my LDS reads of buf u drained, then signal: others may overwrite it
            asm volatile("s_waitcnt lgkmcnt(0)" ::: "memory");
            __builtin_amdgcn_sched_barrier(0);
            __builtin_amdgcn_s_barrier();
            __builtin_amdgcn_sched_barrier(0);

            if (tc + 3 < nt) stage(As[u], Bs[u], tc + 3);
            if (tc + 1 < nt) {
                if (tc + 4 <= nt)      wait_vm<2 * SL>();   // t+1 landed; t+2,t+3 in flight
                else if (tc + 3 == nt) wait_vm<SL>();
                else                   wait_vm<0>();
                __builtin_amdgcn_s_barrier();
                __builtin_amdgcn_sched_barrier(0);
            }
        }
    }

#pragma unroll
    for (int mi = 0; mi < MREP; mi++) {
#pragma unroll
        for (int ni = 0; ni < 4; ni++) {
            int gcol = bn + wn + ni * 16 + l16;
            float bval = 0.0f;
            if (BIAS) bval = bias[gcol];
#pragma unroll
            for (int r = 0; r < 4; r++) {
                int grow = bm + wm + mi * 16 + 4 * g + r;   // C/D: row=(lane>>4)*4+reg, col=lane&15
                float v = acc[mi][ni][r] + bval;
                if (GELU) v = 0.5f * v * (1.0f + erff(v * 0.70710678118654752f));
                if (RESID) v += resid[(size_t)grow * N + gcol];
                if (BF16OUT) Cb[(size_t)grow * N + gcol] = __float2bfloat16(v);
                else Cf[(size_t)grow * N + gcol] = v;
            }
        }
    }
}

// ---------------- MFMA flash attention: softmax(q@k^T*scale + bias) @ v ----------------
// 1D grid 864 = (bb fastest, then qt, then h), XCD-chunked so blocks sharing bias (qt,h)
// and K/V (h,bb) land on one XCD. qkv input is bf16 now.
__global__ __launch_bounds__(256) void attn_kernel(const __hip_bfloat16* __restrict__ qkvb,
                                                   const float* __restrict__ bias,   // [12][576][576] this layer
                                                   unsigned short* __restrict__ o)   // bf16 [4608][768]
{
    const int seq = (blockIdx.x & 7) * 108 + (blockIdx.x >> 3);
    const int bb = seq & 7, qt = (seq >> 3) % 9, h = seq / 72;
    const int q0 = qt * 64;
    const int tid = threadIdx.x;
    const int wq = tid >> 6, lane = tid & 63, g = lane >> 4, l16 = lane & 15;

    __shared__ __align__(16) unsigned short Qs[64 * 72];
    __shared__ __align__(16) unsigned short Ks[64 * 72];
    __shared__ __align__(16) unsigned short Vt[64 * 72];    // V^T: [d][key]
    __shared__ __align__(16) unsigned short Ps[4][16 * 72]; // per-wave P tile [qrow][key]

    {   // stage Q tile: 4 threads/row, 32B each
        int r = tid >> 2, cb = (tid & 3) * 16;
        const int4* s4 = (const int4*)&qkvb[(size_t)(bb * 576 + q0 + r) * 2304 + h * 64 + cb];
        int4* d4 = (int4*)&Qs[r * 72 + cb];
        d4[0] = s4[0]; d4[1] = s4[1];
    }
    __syncthreads();
    bf16x8 qf0 = *(const bf16x8*)&Qs[(wq * 16 + l16) * 72 + g * 8];
    bf16x8 qf1 = *(const bf16x8*)&Qs[(wq * 16 + l16) * 72 + 32 + g * 8];

    float m_r[4] = {-1e30f, -1e30f, -1e30f, -1e30f};
    float l_r[4] = {0.f, 0.f, 0.f, 0.f};
    f32x4 oa[4] = {};
    const float* bias_h = bias + (size_t)h * 576 * 576;
    const float scale = 0.125f;

    for (int kt = 0; kt < 576; kt += 64) {
        {
            int r = tid >> 2, cb = (tid & 3) * 16;
            const int4* s4 = (const int4*)&qkvb[(size_t)(bb * 576 + kt + r) * 2304 + 768 + h * 64 + cb];
            int4* d4 = (int4*)&Ks[r * 72 + cb];
            d4[0] = s4[0]; d4[1] = s4[1];
            int key = tid & 63, d0 = (tid >> 6) * 16;
            const unsigned short* vs = (const unsigned short*)&qkvb[(size_t)(bb * 576 + kt + key) * 2304 + 1536 + h * 64 + d0];
            bf16x8 v0 = *(const bf16x8*)vs;
            bf16x8 v1 = *(const bf16x8*)(vs + 8);
#pragma unroll
            for (int e = 0; e < 8; e++) {
                Vt[(d0 + e) * 72 + key] = (unsigned short)v0[e];
                Vt[(d0 + 8 + e) * 72 + key] = (unsigned short)v1[e];
            }
        }
        __syncthreads();

        float bl[4][4];
#pragma unroll
        for (int kc = 0; kc < 4; kc++)
#pragma unroll
            for (int r = 0; r < 4; r++) {
                int q = q0 + wq * 16 + 4 * g + r;
                bl[kc][r] = bias_h[(size_t)q * 576 + kt + kc * 16 + l16];
            }

        f32x4 sc[4] = {};
#pragma unroll
        for (int kc = 0; kc < 4; kc++) {
            bf16x8 kf0 = *(const bf16x8*)&Ks[(kc * 16 + l16) * 72 + g * 8];
            bf16x8 kf1 = *(const bf16x8*)&Ks[(kc * 16 + l16) * 72 + 32 + g * 8];
            sc[kc] = __builtin_amdgcn_mfma_f32_16x16x32_bf16(qf0, kf0, sc[kc], 0, 0, 0);
            sc[kc] = __builtin_amdgcn_mfma_f32_16x16x32_bf16(qf1, kf1, sc[kc], 0, 0, 0);
        }

        float sv[4][4], mt[4] = {-1e30f, -1e30f, -1e30f, -1e30f};
#pragma unroll
        for (int kc = 0; kc < 4; kc++)
#pragma unroll
            for (int r = 0; r < 4; r++) {
                float s = sc[kc][r] * scale + bl[kc][r];
                sv[kc][r] = s;
                mt[r] = fmaxf(mt[r], s);
            }
#pragma unroll
        for (int r = 0; r < 4; r++)
#pragma unroll
            for (int m = 1; m < 16; m <<= 1) mt[r] = fmaxf(mt[r], __shfl_xor(mt[r], m));

        float sf[4];
#pragma unroll
        for (int r = 0; r < 4; r++) {
            float mn = fmaxf(m_r[r], mt[r]);
            sf[r] = __expf(m_r[r] - mn);
            m_r[r] = mn;
        }
        float rs[4] = {0.f, 0.f, 0.f, 0.f};
#pragma unroll
        for (int kc = 0; kc < 4; kc++)
#pragma unroll
            for (int r = 0; r < 4; r++) {
                float p = __expf(sv[kc][r] - m_r[r]);
                rs[r] += p;
                Ps[wq][(4 * g + r) * 72 + kc * 16 + l16] = f2bf_bits(p);
            }
#pragma unroll
        for (int r = 0; r < 4; r++) {
#pragma unroll
            for (int m = 1; m < 16; m <<= 1) rs[r] += __shfl_xor(rs[r], m);
            l_r[r] = l_r[r] * sf[r] + rs[r];
        }
#pragma unroll
        for (int dt = 0; dt < 4; dt++)
#pragma unroll
            for (int r = 0; r < 4; r++) oa[dt][r] *= sf[r];

        asm volatile("s_waitcnt lgkmcnt(0)" ::: "memory");

#pragma unroll
        for (int s = 0; s < 2; s++) {
            bf16x8 pf = *(const bf16x8*)&Ps[wq][l16 * 72 + s * 32 + g * 8];
#pragma unroll
            for (int dt = 0; dt < 4; dt++) {
                bf16x8 vf = *(const bf16x8*)&Vt[(dt * 16 + l16) * 72 + s * 32 + g * 8];
                oa[dt] = __builtin_amdgcn_mfma_f32_16x16x32_bf16(pf, vf, oa[dt], 0, 0, 0);
            }
        }
        __syncthreads();
    }

#pragma unroll
    for (int dt = 0; dt < 4; dt++)
#pragma unroll
        for (int r = 0; r < 4; r++) {
            int q = q0 + wq * 16 + 4 * g + r;
            float v = oa[dt][r] / l_r[r];
            o[(size_t)(bb * 576 + q) * 768 + h * 64 + dt * 16 + l16] = f2bf_bits(v);
        }
}

// ---------------- mean pool over 576 tokens ----------------
__global__ __launch_bounds__(256) void pool_kernel(const float* __restrict__ tok, float* __restrict__ pooled)
{
    int d = blockIdx.x * 256 + threadIdx.x;   // grid.x = 3
    int b = blockIdx.y;
    float s = 0.0f;
    for (int n = 0; n < 576; n++) s += tok[(size_t)(b * 576 + n) * 768 + d];
    pooled[b * 768 + d] = s * (1.0f / 576.0f);
}

// ---------------- classifier head ----------------
__global__ __launch_bounds__(256) void head_kernel(const float* __restrict__ lnp,
                                                   const float* __restrict__ w,
                                                   const float* __restrict__ bh,
                                                   float* __restrict__ out)
{
    int c = blockIdx.x * 256 + threadIdx.x;
    int b = blockIdx.y;
    if (c >= 1000) return;
    float s = bh[c];
    for (int d = 0; d < 768; d++) s += lnp[b * 768 + d] * w[(size_t)d * 1000 + c];
    out[b * 1000 + c] = s;
}

extern "C" void kernel_launch(void* const* d_in, const int* in_sizes, int n_in,
                              void* d_out, int out_size, void* d_ws, size_t ws_size,
                              hipStream_t stream)
{
    const float* x = (const float*)d_in[0];
    const float* patch_w = (const float*)d_in[1];
    const float* patch_b = (const float*)d_in[2];
    const float* ln1_g = (const float*)d_in[3];
    const float* ln1_b = (const float*)d_in[4];
    const float* w_qkv = (const float*)d_in[5];
    const float* bias_att = (const float*)d_in[6];
    const float* w_out = (const float*)d_in[7];
    const float* ln2_g = (const float*)d_in[8];
    const float* ln2_b = (const float*)d_in[9];
    const float* w1 = (const float*)d_in[10];
    const float* b1 = (const float*)d_in[11];
    const float* w2 = (const float*)d_in[12];
    const float* b2 = (const float*)d_in[13];
    const float* lnh_g = (const float*)d_in[14];
    const float* lnh_b = (const float*)d_in[15];
    const float* w_head = (const float*)d_in[16];
    const float* b_head = (const float*)d_in[17];
    float* out = (float*)d_out;

    char* ws = (char*)d_ws;
    float* tok = (float*)(ws + 0);                               // 4608*768 f32   = 14,155,776 B
    __hip_bfloat16* qkv_bf = (__hip_bfloat16*)(ws + 14155776);   // 4608*2304 bf16 = 21,233,664 B
    float* pooled = (float*)(ws + 56623104);                     // 8*768 f32
    float* pooledln = (float*)(ws + 56647680);                   // 8*768 f32
    __hip_bfloat16* patches = (__hip_bfloat16*)(ws + 56672256);  // 4608*1536 bf16 = 14,155,776 B
    __hip_bfloat16* lw = patches;                                // layer weights reuse patches region
    __hip_bfloat16* h_bf = (__hip_bfloat16*)(ws + 70828032);     // 4608*768 bf16
    __hip_bfloat16* o_bf = (__hip_bfloat16*)(ws + 77905920);     // 4608*768 bf16
    __hip_bfloat16* hid_bf = (__hip_bfloat16*)(ws + 84983808);   // 4608*3072 bf16
    __hip_bfloat16* wbuf = (__hip_bfloat16*)(ws + 113295360);    // patch weight: 1536*768 bf16

    // patch embedding
    patchify_kernel<<<27648, 256, 0, stream>>>(x, (unsigned short*)patches);
    convT_kernel<<<dim3(768 / 32, 1536 / 32), 256, 0, stream>>>(patch_w, wbuf, 1536, 768);
    gemm_bt_kernel<64, true, false, false, false><<<432, 256, 0, stream>>>(
        patches, wbuf, patch_b, nullptr, tok, nullptr, 4608, 768, 1536, 6, 54);

    for (int l = 0; l < 4; l++) {
        convT4_kernel<<<6912, 256, 0, stream>>>(
            w_qkv + (size_t)l * 768 * 2304, w_out + (size_t)l * 768 * 768,
            w1 + (size_t)l * 768 * 3072, w2 + (size_t)l * 3072 * 768, lw);
        // attn sub-block
        ln_kernel<__hip_bfloat16><<<4608, 256, 0, stream>>>(tok, ln1_g + l * 768, ln1_b + l * 768, h_bf);
        gemm_bt_kernel<128, false, false, false, true><<<648, 256, 0, stream>>>(
            h_bf, lw, nullptr, nullptr, nullptr, qkv_bf, 4608, 2304, 768, 18, 81);
        attn_kernel<<<864, 256, 0, stream>>>(
            qkv_bf, bias_att + (size_t)l * 12 * 576 * 576, (unsigned short*)o_bf);
        gemm_bt_kernel<64, false, true, false, false><<<432, 256, 0, stream>>>(
            o_bf, lw + 1769472, nullptr, tok, tok, nullptr, 4608, 768, 768, 6, 54);
        // mlp sub-block
        ln_kernel<__hip_bfloat16><<<4608, 256, 0, stream>>>(tok, ln2_g + l * 768, ln2_b + l * 768, h_bf);
        gemm_bt_kernel<128, true, false, true, true><<<864, 256, 0, stream>>>(
            h_bf, lw + 2359296, b1 + l * 3072, nullptr, nullptr, hid_bf, 4608, 3072, 768, 24, 108);
        gemm_bt_kernel<64, true, true, false, false><<<432, 256, 0, stream>>>(
            hid_bf, lw + 4718592, b2 + l * 768, tok, tok, nullptr, 4608, 768, 3072, 6, 54);
    }

    pool_kernel<<<dim3(3, 8), 256, 0, stream>>>(tok, pooled);
    ln_kernel<float><<<8, 256, 0, stream>>>(pooled, lnh_g, lnh_b, pooledln);
    head_kernel<<<dim3(4, 8), 256, 0, stream>>>(pooledln, w_head, b_head, out);
}

// Round 6
// 910.315 us; speedup vs baseline: 1.2029x; 1.0120x over previous
//
#include <hip/hip_runtime.h>
#include <hip/hip_bf16.h>

typedef __attribute__((ext_vector_type(8))) short bf16x8;
typedef __attribute__((ext_vector_type(4))) float f32x4;

#define DEVI __device__ __forceinline__

DEVI unsigned short f2bf_bits(float f) {
    __hip_bfloat16 h = __float2bfloat16(f);
    return *reinterpret_cast<unsigned short*>(&h);
}

// async global->LDS, 16B per lane. LDS dest is wave-uniform base + lane*16 (linear).
DEVI void gload_lds16(const void* g, void* lds) {
    __builtin_amdgcn_global_load_lds(
        (const __attribute__((address_space(1))) unsigned int*)g,
        (__attribute__((address_space(3))) unsigned int*)lds, 16, 0, 0);
}

template <int N> DEVI void wait_vm() {
    if constexpr (N == 0) asm volatile("s_waitcnt vmcnt(0)" ::: "memory");
    else if constexpr (N == 3) asm volatile("s_waitcnt vmcnt(3)" ::: "memory");
    else if constexpr (N == 6) asm volatile("s_waitcnt vmcnt(6)" ::: "memory");
    else if constexpr (N == 12) asm volatile("s_waitcnt vmcnt(12)" ::: "memory");
    __builtin_amdgcn_sched_barrier(0);
}

// m204 bijective XCD chunking + group-of-4-rows 2D locality. total%8==0 not required.
DEVI int2 remap2d(int bid, int total, int gx) {
    int q = total >> 3, r = total & 7, x = bid & 7, l = bid >> 3;
    int seq = (x < r ? x * (q + 1) : r * (q + 1) + (x - r) * q) + l;
    int g4 = seq / (4 * gx);
    int rem = seq - g4 * 4 * gx;
    return {g4 * 4 + (rem & 3), rem >> 2};   // (by, bx)
}

// ---------------- patchify: x[B,C,384,384] -> patches bf16 [4608][1536] (c-major patch dim) ----
// k' = c*256 + p1*16 + p2  (so 8 consecutive j -> 16B-contiguous store)
__global__ __launch_bounds__(256) void patchify_kernel(const float* __restrict__ x,
                                                       unsigned short* __restrict__ patches)
{
    size_t t8 = (size_t)blockIdx.x * 256 + threadIdx.x;   // 884,736 threads, 8 floats each
    int jq = (int)(t8 % 48);
    size_t t = t8 / 48;
    int r = (int)(t % 384); t /= 384;
    int c = (int)(t % 6);
    int b = (int)(t / 6);
    int j = jq * 8;
    int gh = r >> 4, p1 = r & 15, gw = j >> 4, p2 = j & 15;
    int prow = b * 576 + gh * 24 + gw;
    int pcol = c * 256 + p1 * 16 + p2;
    const float* src = x + ((((size_t)b * 6 + c) * 384 + r) * 384 + j);
    float4 v0 = ((const float4*)src)[0];
    float4 v1 = ((const float4*)src)[1];
    ushort u[8] = { f2bf_bits(v0.x), f2bf_bits(v0.y), f2bf_bits(v0.z), f2bf_bits(v0.w),
                    f2bf_bits(v1.x), f2bf_bits(v1.y), f2bf_bits(v1.z), f2bf_bits(v1.w) };
    *(int4*)&patches[(size_t)prow * 1536 + pcol] = *(int4*)u;
}

// ---------------- patch-weight convert: W f32 [1536][768] -> Wt bf16 [768][1536'] (k-permuted) --
__global__ __launch_bounds__(256) void convT_patch_kernel(const float* __restrict__ W,
                                                          __hip_bfloat16* __restrict__ Wt)
{
    __shared__ float tile[32][33];
    int n0 = blockIdx.x * 32, kp0 = blockIdx.y * 32;
    int tx = threadIdx.x & 31, ty = threadIdx.x >> 5;
#pragma unroll
    for (int i = 0; i < 4; i++) {
        int kp = kp0 + ty + 8 * i;
        int k = (kp & 255) * 6 + (kp >> 8);   // inverse of k' = c*256 + pp
        tile[ty + 8 * i][tx] = W[(size_t)k * 768 + n0 + tx];
    }
    __syncthreads();
#pragma unroll
    for (int i = 0; i < 4; i++)
        Wt[(size_t)(n0 + ty + 8 * i) * 1536 + kp0 + tx] = __float2bfloat16(tile[tx][ty + 8 * i]);
}

// ---------------- weight convert + transpose: W f32 [K][N] -> Wt bf16 [N][K] ----------------
DEVI void convT_body(const float* __restrict__ W, __hip_bfloat16* __restrict__ Wt,
                     int K, int N, int k0, int n0, int tid)
{
    __shared__ float tile[32][33];
    int tx = tid & 31, ty = tid >> 5;
#pragma unroll
    for (int i = 0; i < 4; i++)
        tile[ty + 8 * i][tx] = W[(size_t)(k0 + ty + 8 * i) * N + n0 + tx];
    __syncthreads();
#pragma unroll
    for (int i = 0; i < 4; i++)
        Wt[(size_t)(n0 + ty + 8 * i) * K + k0 + tx] = __float2bfloat16(tile[tx][ty + 8 * i]);
}

// one dispatch converts all 4 weights of a layer into lw:
//   [0) qkv^T [2304][768]  [1769472) wout^T [768][768]
//   [2359296) w1^T [3072][768]  [4718592) w2^T [768][3072]
__global__ __launch_bounds__(256) void convT4_kernel(const float* __restrict__ wqkv,
                                                     const float* __restrict__ wout,
                                                     const float* __restrict__ w1,
                                                     const float* __restrict__ w2,
                                                     __hip_bfloat16* __restrict__ dst)
{
    int bt = blockIdx.x;
    const float* W; __hip_bfloat16* Wt; int K, N, lt;
    if (bt < 1728)      { W = wqkv; K = 768;  N = 2304; lt = bt;        Wt = dst; }
    else if (bt < 2304) { W = wout; K = 768;  N = 768;  lt = bt - 1728; Wt = dst + 1769472; }
    else if (bt < 4608) { W = w1;   K = 768;  N = 3072; lt = bt - 2304; Wt = dst + 2359296; }
    else                { W = w2;   K = 3072; N = 768;  lt = bt - 4608; Wt = dst + 4718592; }
    int tn = N >> 5;
    convT_body(W, Wt, K, N, (lt / tn) * 32, (lt % tn) * 32, threadIdx.x);
}

// ---------------- layernorm over 768 cols ----------------
DEVI void st_ln(float* p, float v) { *p = v; }
DEVI void st_ln(__hip_bfloat16* p, float v) { *p = __float2bfloat16(v); }

template <typename OutT>
__global__ __launch_bounds__(256) void ln_kernel(const float* __restrict__ x,
                                                 const float* __restrict__ g,
                                                 const float* __restrict__ b,
                                                 OutT* __restrict__ out)
{
    int row = blockIdx.x, tid = threadIdx.x;
    const float* xr = x + (size_t)row * 768;
    float v0 = xr[tid], v1 = xr[tid + 256], v2 = xr[tid + 512];
    float s = v0 + v1 + v2;
    float s2 = v0 * v0 + v1 * v1 + v2 * v2;
#pragma unroll
    for (int m = 32; m >= 1; m >>= 1) { s += __shfl_xor(s, m); s2 += __shfl_xor(s2, m); }
    __shared__ float red[8];
    int w = tid >> 6;
    if ((tid & 63) == 0) { red[w] = s; red[4 + w] = s2; }
    __syncthreads();
    s = red[0] + red[1] + red[2] + red[3];
    s2 = red[4] + red[5] + red[6] + red[7];
    float mean = s * (1.0f / 768.0f);
    float var = s2 * (1.0f / 768.0f) - mean * mean;
    float rstd = rsqrtf(var + 1e-5f);
    OutT* orow = out + (size_t)row * 768;
    st_ln(&orow[tid], (v0 - mean) * rstd * g[tid] + b[tid]);
    st_ln(&orow[tid + 256], (v1 - mean) * rstd * g[tid + 256] + b[tid + 256]);
    st_ln(&orow[tid + 512], (v2 - mean) * rstd * g[tid + 512] + b[tid + 512]);
}

// ---------------- narrow GEMM: BM=64 x BN=128, 3-deep counted-vmcnt (unchanged core) ----------
template <bool BIAS, bool RESID, bool GELU>
__global__ __launch_bounds__(256, 3) void gemm_bt_kernel(
    const __hip_bfloat16* __restrict__ A,
    const __hip_bfloat16* __restrict__ Bt,
    const float* __restrict__ bias,
    const float* __restrict__ resid,
    float* __restrict__ Cf,
    int M, int N, int K, int gx)
{
    constexpr int BM = 64, SL = 3;
    __shared__ __align__(16) __hip_bfloat16 As[3][BM * 32];
    __shared__ __align__(16) __hip_bfloat16 Bs[3][128 * 32];
    const int tid = threadIdx.x;
    const int wid = tid >> 6, lane = tid & 63;
    const int g = lane >> 4, l16 = lane & 15;
    const int wm = (wid >> 1) * 32, wn = (wid & 1) * 64;

    int2 bc = remap2d(blockIdx.x, gridDim.x, gx);
    const int bm = bc.x * BM, bn = bc.y * 128;

    const int sr = tid >> 2;
    const int csrc = (lane & 3) ^ ((lane >> 3) & 3);
    const int sdst = sr * 32 + (lane & 3) * 8;
    size_t aOff = (size_t)(bm + sr) * K + csrc * 8;
    size_t bOff[2];
#pragma unroll
    for (int i = 0; i < 2; i++) bOff[i] = (size_t)(bn + i * 64 + sr) * K + csrc * 8;

    auto stage = [&](__hip_bfloat16* asb, __hip_bfloat16* bsb, int tq) {
        const __hip_bfloat16* ap = A + tq * 32;
        const __hip_bfloat16* bp = Bt + tq * 32;
        gload_lds16(ap + aOff, asb + sdst);
#pragma unroll
        for (int i = 0; i < 2; i++) gload_lds16(bp + bOff[i], bsb + i * 2048 + sdst);
    };

    const int pSw = (l16 >> 1) & 3;
    f32x4 acc[2][4] = {};
    const int nt = K >> 5;

    stage(As[0], Bs[0], 0);
    stage(As[1], Bs[1], 1);
    stage(As[2], Bs[2], 2);
    wait_vm<2 * SL>();
    __builtin_amdgcn_s_barrier();
    __builtin_amdgcn_sched_barrier(0);

    for (int t = 0; t < nt; t += 3) {
#pragma unroll
        for (int u = 0; u < 3; u++) {
            const int tc = t + u;
            bf16x8 af[2], bfr[4];
#pragma unroll
            for (int mi = 0; mi < 2; mi++)
                af[mi] = *(const bf16x8*)&As[u][(wm + mi * 16 + l16) * 32 + ((g ^ pSw) << 3)];
#pragma unroll
            for (int ni = 0; ni < 4; ni++)
                bfr[ni] = *(const bf16x8*)&Bs[u][(wn + ni * 16 + l16) * 32 + ((g ^ pSw) << 3)];
            __builtin_amdgcn_s_setprio(1);
#pragma unroll
            for (int mi = 0; mi < 2; mi++)
#pragma unroll
                for (int ni = 0; ni < 4; ni++)
                    acc[mi][ni] = __builtin_amdgcn_mfma_f32_16x16x32_bf16(af[mi], bfr[ni], acc[mi][ni], 0, 0, 0);
            __builtin_amdgcn_s_setprio(0);

            asm volatile("s_waitcnt lgkmcnt(0)" ::: "memory");
            __builtin_amdgcn_sched_barrier(0);
            __builtin_amdgcn_s_barrier();
            __builtin_amdgcn_sched_barrier(0);

            if (tc + 3 < nt) stage(As[u], Bs[u], tc + 3);
            if (tc + 1 < nt) {
                if (tc + 4 <= nt)      wait_vm<2 * SL>();
                else if (tc + 3 == nt) wait_vm<SL>();
                else                   wait_vm<0>();
                __builtin_amdgcn_s_barrier();
                __builtin_amdgcn_sched_barrier(0);
            }
        }
    }

#pragma unroll
    for (int mi = 0; mi < 2; mi++) {
#pragma unroll
        for (int ni = 0; ni < 4; ni++) {
            int gcol = bn + wn + ni * 16 + l16;
            float bval = 0.0f;
            if (BIAS) bval = bias[gcol];
#pragma unroll
            for (int r = 0; r < 4; r++) {
                int grow = bm + wm + mi * 16 + 4 * g + r;
                float v = acc[mi][ni][r] + bval;
                if (GELU) v = 0.5f * v * (1.0f + erff(v * 0.70710678118654752f));
                if (RESID) v += resid[(size_t)grow * N + gcol];
                Cf[(size_t)grow * N + gcol] = v;
            }
        }
    }
}

// ---------------- wide GEMM: BM=128 x BN=256, BK=32, 4 waves (2Mx2N of 64x128), bf16 out ------
// 32 MFMA / 12 ds_read per step per wave (2x density of narrow); 3-deep counted vmcnt;
// coalesced epilogue through per-wave LDS transpose (16B stores).
template <bool BIAS, bool GELU>
__global__ __launch_bounds__(256, 2) void gemm_wide_kernel(
    const __hip_bfloat16* __restrict__ A,
    const __hip_bfloat16* __restrict__ Bt,
    const float* __restrict__ bias,
    __hip_bfloat16* __restrict__ Cb,
    int M, int N, int K, int gx)
{
    constexpr int SL = 6;   // 2 A-loads + 4 B-loads per thread per tile
    __shared__ __align__(16) __hip_bfloat16 As[3][128 * 32];
    __shared__ __align__(16) __hip_bfloat16 Bs[3][256 * 32];
    const int tid = threadIdx.x;
    const int wid = tid >> 6, lane = tid & 63;
    const int g = lane >> 4, l16 = lane & 15;
    const int wm = (wid >> 1) * 64, wn = (wid & 1) * 128;

    int2 bc = remap2d(blockIdx.x, gridDim.x, gx);
    const int bm = bc.x * 128, bn = bc.y * 256;

    const int sr = tid >> 2;
    const int csrc = (lane & 3) ^ ((lane >> 3) & 3);
    const int sdst = sr * 32 + (lane & 3) * 8;
    size_t aOff[2], bOff[4];
#pragma unroll
    for (int i = 0; i < 2; i++) aOff[i] = (size_t)(bm + i * 64 + sr) * K + csrc * 8;
#pragma unroll
    for (int i = 0; i < 4; i++) bOff[i] = (size_t)(bn + i * 64 + sr) * K + csrc * 8;

    auto stage = [&](__hip_bfloat16* asb, __hip_bfloat16* bsb, int tq) {
        const __hip_bfloat16* ap = A + tq * 32;
        const __hip_bfloat16* bp = Bt + tq * 32;
#pragma unroll
        for (int i = 0; i < 2; i++) gload_lds16(ap + aOff[i], asb + i * 2048 + sdst);
#pragma unroll
        for (int i = 0; i < 4; i++) gload_lds16(bp + bOff[i], bsb + i * 2048 + sdst);
    };

    const int pSw = (l16 >> 1) & 3;
    f32x4 acc[4][8] = {};
    const int nt = K >> 5;   // 24 for K=768

    stage(As[0], Bs[0], 0);
    stage(As[1], Bs[1], 1);
    stage(As[2], Bs[2], 2);
    wait_vm<2 * SL>();
    __builtin_amdgcn_s_barrier();
    __builtin_amdgcn_sched_barrier(0);

    for (int t = 0; t < nt; t += 3) {
#pragma unroll
        for (int u = 0; u < 3; u++) {
            const int tc = t + u;
            bf16x8 af[4], bfr[8];
#pragma unroll
            for (int mi = 0; mi < 4; mi++)
                af[mi] = *(const bf16x8*)&As[u][(wm + mi * 16 + l16) * 32 + ((g ^ pSw) << 3)];
#pragma unroll
            for (int ni = 0; ni < 8; ni++)
                bfr[ni] = *(const bf16x8*)&Bs[u][(wn + ni * 16 + l16) * 32 + ((g ^ pSw) << 3)];
            __builtin_amdgcn_s_setprio(1);
#pragma unroll
            for (int mi = 0; mi < 4; mi++)
#pragma unroll
                for (int ni = 0; ni < 8; ni++)
                    acc[mi][ni] = __builtin_amdgcn_mfma_f32_16x16x32_bf16(af[mi], bfr[ni], acc[mi][ni], 0, 0, 0);
            __builtin_amdgcn_s_setprio(0);

            asm volatile("s_waitcnt lgkmcnt(0)" ::: "memory");
            __builtin_amdgcn_sched_barrier(0);
            __builtin_amdgcn_s_barrier();
            __builtin_amdgcn_sched_barrier(0);

            if (tc + 3 < nt) stage(As[u], Bs[u], tc + 3);
            if (tc + 1 < nt) {
                if (tc + 4 <= nt)      wait_vm<2 * SL>();
                else if (tc + 3 == nt) wait_vm<SL>();
                else                   wait_vm<0>();
                __builtin_amdgcn_s_barrier();
                __builtin_amdgcn_sched_barrier(0);
            }
        }
    }

    // coalesced epilogue: per-wave LDS transpose, rows padded to 136 elems (272B, 16B-aligned)
    __hip_bfloat16* scr = &As[0][0] + wid * (16 * 136);
#pragma unroll
    for (int mi = 0; mi < 4; mi++) {
#pragma unroll
        for (int ni = 0; ni < 8; ni++) {
            int gcol = bn + wn + ni * 16 + l16;
            float bval = 0.0f;
            if (BIAS) bval = bias[gcol];
#pragma unroll
            for (int r = 0; r < 4; r++) {
                float v = acc[mi][ni][r] + bval;
                if (GELU) v = 0.5f * v * (1.0f + erff(v * 0.70710678118654752f));
                scr[(4 * g + r) * 136 + ni * 16 + l16] = __float2bfloat16(v);
            }
        }
        asm volatile("s_waitcnt lgkmcnt(0)" ::: "memory");
        __builtin_amdgcn_sched_barrier(0);
#pragma unroll
        for (int q2 = 0; q2 < 4; q2++) {
            int idx = q2 * 64 + lane;
            int row16 = idx >> 4, ch = idx & 15;
            bf16x8 vv = *(const bf16x8*)&scr[row16 * 136 + ch * 8];
            int grow = bm + wm + mi * 16 + row16;
            *(int4*)&Cb[(size_t)grow * N + bn + wn + ch * 8] = *(int4*)&vv;
        }
        asm volatile("s_waitcnt lgkmcnt(0)" ::: "memory");
        __builtin_amdgcn_sched_barrier(0);
    }
}

// ---------------- MFMA flash attention: softmax(q@k^T*scale + bias) @ v ----------------
__global__ __launch_bounds__(256) void attn_kernel(const __hip_bfloat16* __restrict__ qkvb,
                                                   const float* __restrict__ bias,   // [12][576][576] this layer
                                                   unsigned short* __restrict__ o)   // bf16 [4608][768]
{
    const int seq = (blockIdx.x & 7) * 108 + (blockIdx.x >> 3);
    const int bb = seq & 7, qt = (seq >> 3) % 9, h = seq / 72;
    const int q0 = qt * 64;
    const int tid = threadIdx.x;
    const int wq = tid >> 6, lane = tid & 63, g = lane >> 4, l16 = lane & 15;

    __shared__ __align__(16) unsigned short Qs[64 * 72];
    __shared__ __align__(16) unsigned short Ks[64 * 72];
    __shared__ __align__(16) unsigned short Vt[64 * 72];
    __shared__ __align__(16) unsigned short Ps[4][16 * 72];

    {
        int r = tid >> 2, cb = (tid & 3) * 16;
        const int4* s4 = (const int4*)&qkvb[(size_t)(bb * 576 + q0 + r) * 2304 + h * 64 + cb];
        int4* d4 = (int4*)&Qs[r * 72 + cb];
        d4[0] = s4[0]; d4[1] = s4[1];
    }
    __syncthreads();
    bf16x8 qf0 = *(const bf16x8*)&Qs[(wq * 16 + l16) * 72 + g * 8];
    bf16x8 qf1 = *(const bf16x8*)&Qs[(wq * 16 + l16) * 72 + 32 + g * 8];

    float m_r[4] = {-1e30f, -1e30f, -1e30f, -1e30f};
    float l_r[4] = {0.f, 0.f, 0.f, 0.f};
    f32x4 oa[4] = {};
    const float* bias_h = bias + (size_t)h * 576 * 576;
    const float scale = 0.125f;

    for (int kt = 0; kt < 576; kt += 64) {
        {
            int r = tid >> 2, cb = (tid & 3) * 16;
            const int4* s4 = (const int4*)&qkvb[(size_t)(bb * 576 + kt + r) * 2304 + 768 + h * 64 + cb];
            int4* d4 = (int4*)&Ks[r * 72 + cb];
            d4[0] = s4[0]; d4[1] = s4[1];
            int key = tid & 63, d0 = (tid >> 6) * 16;
            const unsigned short* vs = (const unsigned short*)&qkvb[(size_t)(bb * 576 + kt + key) * 2304 + 1536 + h * 64 + d0];
            bf16x8 v0 = *(const bf16x8*)vs;
            bf16x8 v1 = *(const bf16x8*)(vs + 8);
#pragma unroll
            for (int e = 0; e < 8; e++) {
                Vt[(d0 + e) * 72 + key] = (unsigned short)v0[e];
                Vt[(d0 + 8 + e) * 72 + key] = (unsigned short)v1[e];
            }
        }
        __syncthreads();

        float bl[4][4];
#pragma unroll
        for (int kc = 0; kc < 4; kc++)
#pragma unroll
            for (int r = 0; r < 4; r++) {
                int q = q0 + wq * 16 + 4 * g + r;
                bl[kc][r] = bias_h[(size_t)q * 576 + kt + kc * 16 + l16];
            }

        f32x4 sc[4] = {};
        __builtin_amdgcn_s_setprio(1);
#pragma unroll
        for (int kc = 0; kc < 4; kc++) {
            bf16x8 kf0 = *(const bf16x8*)&Ks[(kc * 16 + l16) * 72 + g * 8];
            bf16x8 kf1 = *(const bf16x8*)&Ks[(kc * 16 + l16) * 72 + 32 + g * 8];
            sc[kc] = __builtin_amdgcn_mfma_f32_16x16x32_bf16(qf0, kf0, sc[kc], 0, 0, 0);
            sc[kc] = __builtin_amdgcn_mfma_f32_16x16x32_bf16(qf1, kf1, sc[kc], 0, 0, 0);
        }
        __builtin_amdgcn_s_setprio(0);

        float sv[4][4], mt[4] = {-1e30f, -1e30f, -1e30f, -1e30f};
#pragma unroll
        for (int kc = 0; kc < 4; kc++)
#pragma unroll
            for (int r = 0; r < 4; r++) {
                float s = sc[kc][r] * scale + bl[kc][r];
                sv[kc][r] = s;
                mt[r] = fmaxf(mt[r], s);
            }
#pragma unroll
        for (int r = 0; r < 4; r++)
#pragma unroll
            for (int m = 1; m < 16; m <<= 1) mt[r] = fmaxf(mt[r], __shfl_xor(mt[r], m));

        float sf[4];
#pragma unroll
        for (int r = 0; r < 4; r++) {
            float mn = fmaxf(m_r[r], mt[r]);
            sf[r] = __expf(m_r[r] - mn);
            m_r[r] = mn;
        }
        float rs[4] = {0.f, 0.f, 0.f, 0.f};
#pragma unroll
        for (int kc = 0; kc < 4; kc++)
#pragma unroll
            for (int r = 0; r < 4; r++) {
                float p = __expf(sv[kc][r] - m_r[r]);
                rs[r] += p;
                Ps[wq][(4 * g + r) * 72 + kc * 16 + l16] = f2bf_bits(p);
            }
#pragma unroll
        for (int r = 0; r < 4; r++) {
#pragma unroll
            for (int m = 1; m < 16; m <<= 1) rs[r] += __shfl_xor(rs[r], m);
            l_r[r] = l_r[r] * sf[r] + rs[r];
        }
#pragma unroll
        for (int dt = 0; dt < 4; dt++)
#pragma unroll
            for (int r = 0; r < 4; r++) oa[dt][r] *= sf[r];

        asm volatile("s_waitcnt lgkmcnt(0)" ::: "memory");

        __builtin_amdgcn_s_setprio(1);
#pragma unroll
        for (int s = 0; s < 2; s++) {
            bf16x8 pf = *(const bf16x8*)&Ps[wq][l16 * 72 + s * 32 + g * 8];
#pragma unroll
            for (int dt = 0; dt < 4; dt++) {
                bf16x8 vf = *(const bf16x8*)&Vt[(dt * 16 + l16) * 72 + s * 32 + g * 8];
                oa[dt] = __builtin_amdgcn_mfma_f32_16x16x32_bf16(pf, vf, oa[dt], 0, 0, 0);
            }
        }
        __builtin_amdgcn_s_setprio(0);
        __syncthreads();
    }

#pragma unroll
    for (int dt = 0; dt < 4; dt++)
#pragma unroll
        for (int r = 0; r < 4; r++) {
            int q = q0 + wq * 16 + 4 * g + r;
            float v = oa[dt][r] / l_r[r];
            o[(size_t)(bb * 576 + q) * 768 + h * 64 + dt * 16 + l16] = f2bf_bits(v);
        }
}

// ---------------- mean pool over 576 tokens ----------------
__global__ __launch_bounds__(256) void pool_kernel(const float* __restrict__ tok, float* __restrict__ pooled)
{
    int d = blockIdx.x * 256 + threadIdx.x;
    int b = blockIdx.y;
    float s = 0.0f;
    for (int n = 0; n < 576; n++) s += tok[(size_t)(b * 576 + n) * 768 + d];
    pooled[b * 768 + d] = s * (1.0f / 576.0f);
}

// ---------------- classifier head ----------------
__global__ __launch_bounds__(256) void head_kernel(const float* __restrict__ lnp,
                                                   const float* __restrict__ w,
                                                   const float* __restrict__ bh,
                                                   float* __restrict__ out)
{
    int c = blockIdx.x * 256 + threadIdx.x;
    int b = blockIdx.y;
    if (c >= 1000) return;
    float s = bh[c];
    for (int d = 0; d < 768; d++) s += lnp[b * 768 + d] * w[(size_t)d * 1000 + c];
    out[b * 1000 + c] = s;
}

extern "C" void kernel_launch(void* const* d_in, const int* in_sizes, int n_in,
                              void* d_out, int out_size, void* d_ws, size_t ws_size,
                              hipStream_t stream)
{
    const float* x = (const float*)d_in[0];
    const float* patch_w = (const float*)d_in[1];
    const float* patch_b = (const float*)d_in[2];
    const float* ln1_g = (const float*)d_in[3];
    const float* ln1_b = (const float*)d_in[4];
    const float* w_qkv = (const float*)d_in[5];
    const float* bias_att = (const float*)d_in[6];
    const float* w_out = (const float*)d_in[7];
    const float* ln2_g = (const float*)d_in[8];
    const float* ln2_b = (const float*)d_in[9];
    const float* w1 = (const float*)d_in[10];
    const float* b1 = (const float*)d_in[11];
    const float* w2 = (const float*)d_in[12];
    const float* b2 = (const float*)d_in[13];
    const float* lnh_g = (const float*)d_in[14];
    const float* lnh_b = (const float*)d_in[15];
    const float* w_head = (const float*)d_in[16];
    const float* b_head = (const float*)d_in[17];
    float* out = (float*)d_out;

    char* ws = (char*)d_ws;
    float* tok = (float*)(ws + 0);                               // 4608*768 f32
    __hip_bfloat16* qkv_bf = (__hip_bfloat16*)(ws + 14155776);   // 4608*2304 bf16
    float* pooled = (float*)(ws + 56623104);
    float* pooledln = (float*)(ws + 56647680);
    __hip_bfloat16* patches = (__hip_bfloat16*)(ws + 56672256);  // 4608*1536 bf16
    __hip_bfloat16* lw = patches;                                // layer weights reuse after patch GEMM
    __hip_bfloat16* h_bf = (__hip_bfloat16*)(ws + 70828032);
    __hip_bfloat16* o_bf = (__hip_bfloat16*)(ws + 77905920);
    __hip_bfloat16* hid_bf = (__hip_bfloat16*)(ws + 84983808);
    __hip_bfloat16* wbuf = (__hip_bfloat16*)(ws + 113295360);    // patch weight 768*1536 bf16

    // patch embedding (c-major patch-dim layout on both operands)
    patchify_kernel<<<3456, 256, 0, stream>>>(x, (unsigned short*)patches);
    convT_patch_kernel<<<dim3(24, 48), 256, 0, stream>>>(patch_w, wbuf);
    gemm_bt_kernel<true, false, false><<<432, 256, 0, stream>>>(
        patches, wbuf, patch_b, nullptr, tok, 4608, 768, 1536, 6);

    for (int l = 0; l < 4; l++) {
        convT4_kernel<<<6912, 256, 0, stream>>>(
            w_qkv + (size_t)l * 768 * 2304, w_out + (size_t)l * 768 * 768,
            w1 + (size_t)l * 768 * 3072, w2 + (size_t)l * 3072 * 768, lw);
        // attn sub-block
        ln_kernel<__hip_bfloat16><<<4608, 256, 0, stream>>>(tok, ln1_g + l * 768, ln1_b + l * 768, h_bf);
        gemm_wide_kernel<false, false><<<324, 256, 0, stream>>>(
            h_bf, lw, nullptr, qkv_bf, 4608, 2304, 768, 9);
        attn_kernel<<<864, 256, 0, stream>>>(
            qkv_bf, bias_att + (size_t)l * 12 * 576 * 576, (unsigned short*)o_bf);
        gemm_bt_kernel<false, true, false><<<432, 256, 0, stream>>>(
            o_bf, lw + 1769472, nullptr, tok, tok, 4608, 768, 768, 6);
        // mlp sub-block
        ln_kernel<__hip_bfloat16><<<4608, 256, 0, stream>>>(tok, ln2_g + l * 768, ln2_b + l * 768, h_bf);
        gemm_wide_kernel<true, true><<<432, 256, 0, stream>>>(
            h_bf, lw + 2359296, b1 + l * 3072, hid_bf, 4608, 3072, 768, 12);
        gemm_bt_kernel<true, true, false><<<432, 256, 0, stream>>>(
            hid_bf, lw + 4718592, b2 + l * 768, tok, tok, 4608, 768, 3072, 6);
    }

    pool_kernel<<<dim3(3, 8), 256, 0, stream>>>(tok, pooled);
    ln_kernel<float><<<8, 256, 0, stream>>>(pooled, lnh_g, lnh_b, pooledln);
    head_kernel<<<dim3(4, 8), 256, 0, stream>>>(pooledln, w_head, b_head, out);
}